// Round 1
// baseline (715.425 us; speedup 1.0000x reference)
//
#include <hip/hip_runtime.h>

#define N_NODES 100000
#define N_EDGES 300000
#define NB 1024

// ---------------- workspace layout (floats) ----------------
#define OFF_X1    0            // 100000*64  = 6.4M
#define OFF_X2    6400000      // 100000*128 = 12.8M
#define OFF_AGG   19200000     // max 100000*128 = 12.8M (reused for agg0/agg1/agg2)
#define OFF_X3B   32000000     // 1024*256 = 262144
#define OFF_POOL  32262144     // 256
#define OFF_BMEAN 32262400     // 3

// boundary mean of vs -> bmean[3]
__global__ void bmean_kernel(const float* __restrict__ vs, const int* __restrict__ bidx,
                             float* __restrict__ bmean) {
    int tid = threadIdx.x;
    float s0 = 0.f, s1 = 0.f, s2 = 0.f;
    for (int i = tid; i < NB; i += 256) {
        int n = bidx[i];
        s0 += vs[n * 3 + 0];
        s1 += vs[n * 3 + 1];
        s2 += vs[n * 3 + 2];
    }
    for (int off = 32; off > 0; off >>= 1) {
        s0 += __shfl_down(s0, off);
        s1 += __shfl_down(s1, off);
        s2 += __shfl_down(s2, off);
    }
    __shared__ float red[4][3];
    int wave = tid >> 6;
    if ((tid & 63) == 0) { red[wave][0] = s0; red[wave][1] = s1; red[wave][2] = s2; }
    __syncthreads();
    if (tid == 0) {
        float t0 = 0, t1 = 0, t2 = 0;
        for (int w = 0; w < 4; w++) { t0 += red[w][0]; t1 += red[w][1]; t2 += red[w][2]; }
        bmean[0] = t0 / NB; bmean[1] = t1 / NB; bmean[2] = t2 / NB;
    }
}

// agg (3ch) scatter: one thread per edge, both directions
__global__ void scatter3_kernel(const float* __restrict__ x, const int2* __restrict__ edges,
                                float* __restrict__ agg) {
    int e = blockIdx.x * blockDim.x + threadIdx.x;
    if (e >= N_EDGES) return;
    int2 ed = edges[e];
    #pragma unroll
    for (int c = 0; c < 3; c++) {
        atomicAdd(&agg[ed.y * 3 + c], x[ed.x * 3 + c]);
        atomicAdd(&agg[ed.x * 3 + c], x[ed.y * 3 + c]);
    }
}

// conv0: 3 -> 64, relu. block = 4 nodes x 64 couts
__global__ void conv0_kernel(const float* __restrict__ x, const float* __restrict__ agg,
                             const float* __restrict__ Ws, const float* __restrict__ Wn,
                             const float* __restrict__ b, float* __restrict__ out) {
    __shared__ float ws_l[192], wn_l[192], b_l[64];
    int tid = threadIdx.x;
    if (tid < 192) { ws_l[tid] = Ws[tid]; wn_l[tid] = Wn[tid]; }
    if (tid < 64) b_l[tid] = b[tid];
    __syncthreads();
    int n = blockIdx.x * 4 + (tid >> 6);
    int j = tid & 63;
    if (n >= N_NODES) return;
    float x0 = x[n * 3 + 0], x1v = x[n * 3 + 1], x2v = x[n * 3 + 2];
    float a0 = agg[n * 3 + 0], a1 = agg[n * 3 + 1], a2 = agg[n * 3 + 2];
    float acc = b_l[j];
    acc = fmaf(x0, ws_l[0 * 64 + j], acc);
    acc = fmaf(x1v, ws_l[1 * 64 + j], acc);
    acc = fmaf(x2v, ws_l[2 * 64 + j], acc);
    acc = fmaf(a0, wn_l[0 * 64 + j], acc);
    acc = fmaf(a1, wn_l[1 * 64 + j], acc);
    acc = fmaf(a2, wn_l[2 * 64 + j], acc);
    out[n * 64 + j] = fmaxf(acc, 0.f);
}

// generic C-channel scatter: thread = (edge, channel)
template <int LOG2C>
__global__ void scatterC_kernel(const float* __restrict__ x, const int2* __restrict__ edges,
                                float* __restrict__ agg) {
    const int C = 1 << LOG2C;
    int gid = blockIdx.x * blockDim.x + threadIdx.x;
    int e = gid >> LOG2C;
    int c = gid & (C - 1);
    if (e >= N_EDGES) return;
    int2 ed = edges[e];
    float vx = x[ed.x * C + c];
    float vy = x[ed.y * C + c];
    atomicAdd(&agg[ed.y * C + c], vx);
    atomicAdd(&agg[ed.x * C + c], vy);
}

// generic conv: CIN -> COUT, relu. 64-node tile in LDS.
// 256 threads = 64 cout-lanes x 4 groups; each thread does 16 nodes x (COUT/64) couts.
// idx==nullptr: dense rows [0,nrows). idx!=nullptr: gather rows idx[g], compact output.
template <int CIN, int COUT>
__global__ __launch_bounds__(256) void convN_kernel(
    const float* __restrict__ x, const float* __restrict__ agg,
    const float* __restrict__ Ws, const float* __restrict__ Wn,
    const float* __restrict__ b, float* __restrict__ out,
    const int* __restrict__ idx, int nrows) {
    const int JT = COUT / 64;
    __shared__ float xs[64 * CIN];
    __shared__ float as[64 * CIN];
    int tid = threadIdx.x;
    int gbase = blockIdx.x * 64;
    for (int i = tid; i < 64 * CIN; i += 256) {
        int nl = i / CIN;
        int c = i % CIN;
        int ng = gbase + nl;
        float xv = 0.f, av = 0.f;
        if (ng < nrows) {
            int row = idx ? idx[ng] : ng;
            xv = x[row * CIN + c];
            av = agg[row * CIN + c];
        }
        xs[i] = xv;
        as[i] = av;
    }
    __syncthreads();
    int j = tid & 63;
    int g = tid >> 6;
    float acc[16][JT];
    #pragma unroll
    for (int jt = 0; jt < JT; jt++) {
        float bv = b[jt * 64 + j];
        #pragma unroll
        for (int k = 0; k < 16; k++) acc[k][jt] = bv;
    }
    #pragma unroll 4
    for (int c = 0; c < CIN; c++) {
        float wsv[JT], wnv[JT];
        #pragma unroll
        for (int jt = 0; jt < JT; jt++) {
            wsv[jt] = Ws[c * COUT + jt * 64 + j];
            wnv[jt] = Wn[c * COUT + jt * 64 + j];
        }
        #pragma unroll
        for (int k = 0; k < 16; k++) {
            float xv = xs[(g * 16 + k) * CIN + c];
            float av = as[(g * 16 + k) * CIN + c];
            #pragma unroll
            for (int jt = 0; jt < JT; jt++)
                acc[k][jt] = fmaf(xv, wsv[jt], fmaf(av, wnv[jt], acc[k][jt]));
        }
    }
    #pragma unroll
    for (int k = 0; k < 16; k++) {
        int ng = gbase + g * 16 + k;
        if (ng < nrows) {
            #pragma unroll
            for (int jt = 0; jt < JT; jt++)
                out[ng * COUT + jt * 64 + j] = fmaxf(acc[k][jt], 0.f);
        }
    }
}

// pooled sum over 1024 boundary rows of x3b (compact 1024x256)
__global__ void pool_kernel(const float* __restrict__ x3b, float* __restrict__ pooled) {
    int j = threadIdx.x;
    int r0 = blockIdx.x * 32;
    float s = 0.f;
    for (int r = 0; r < 32; r++) s += x3b[(r0 + r) * 256 + j];
    atomicAdd(&pooled[j], s);
}

// head: pooled/1024 -> fc(relu) -> out(12) + bmean broadcast
__global__ void head_kernel(const float* __restrict__ pooled_sum, const float* __restrict__ bmean,
                            const float* __restrict__ Wd, const float* __restrict__ bd,
                            const float* __restrict__ Wo, const float* __restrict__ bo,
                            float* __restrict__ out) {
    __shared__ float p_l[256], h_l[256];
    int tid = threadIdx.x;
    p_l[tid] = pooled_sum[tid] * (1.0f / NB);
    __syncthreads();
    float acc = bd[tid];
    for (int c = 0; c < 256; c++) acc = fmaf(p_l[c], Wd[c * 256 + tid], acc);
    h_l[tid] = fmaxf(acc, 0.f);
    __syncthreads();
    if (tid < 12) {
        float o = bo[tid];
        for (int c = 0; c < 256; c++) o = fmaf(h_l[c], Wo[c * 12 + tid], o);
        out[tid] = o + bmean[tid % 3];
    }
}

extern "C" void kernel_launch(void* const* d_in, const int* in_sizes, int n_in,
                              void* d_out, int out_size, void* d_ws, size_t ws_size,
                              hipStream_t stream) {
    const float* vs   = (const float*)d_in[0];
    const int2*  edges = (const int2*)d_in[1];
    const int*   bidx = (const int*)d_in[2];
    const float* Ws0 = (const float*)d_in[4];
    const float* Wn0 = (const float*)d_in[5];
    const float* b0  = (const float*)d_in[6];
    const float* Ws1 = (const float*)d_in[7];
    const float* Wn1 = (const float*)d_in[8];
    const float* b1  = (const float*)d_in[9];
    const float* Ws2 = (const float*)d_in[10];
    const float* Wn2 = (const float*)d_in[11];
    const float* b2  = (const float*)d_in[12];
    const float* Wd  = (const float*)d_in[13];
    const float* bd  = (const float*)d_in[14];
    const float* Wo  = (const float*)d_in[15];
    const float* bo  = (const float*)d_in[16];

    float* ws = (float*)d_ws;
    float* x1     = ws + OFF_X1;
    float* x2     = ws + OFF_X2;
    float* agg    = ws + OFF_AGG;
    float* x3b    = ws + OFF_X3B;
    float* pooled = ws + OFF_POOL;
    float* bmean  = ws + OFF_BMEAN;
    float* outp   = (float*)d_out;

    bmean_kernel<<<1, 256, 0, stream>>>(vs, bidx, bmean);

    // layer 0
    hipMemsetAsync(agg, 0, (size_t)N_NODES * 3 * sizeof(float), stream);
    scatter3_kernel<<<(N_EDGES + 255) / 256, 256, 0, stream>>>(vs, edges, agg);
    conv0_kernel<<<N_NODES / 4, 256, 0, stream>>>(vs, agg, Ws0, Wn0, b0, x1);

    // layer 1
    hipMemsetAsync(agg, 0, (size_t)N_NODES * 64 * sizeof(float), stream);
    scatterC_kernel<6><<<(N_EDGES * 64) / 256, 256, 0, stream>>>(x1, edges, agg);
    convN_kernel<64, 128><<<(N_NODES + 63) / 64, 256, 0, stream>>>(
        x1, agg, Ws1, Wn1, b1, x2, nullptr, N_NODES);

    // layer 2 (only boundary rows need conv output)
    hipMemsetAsync(agg, 0, (size_t)N_NODES * 128 * sizeof(float), stream);
    scatterC_kernel<7><<<(N_EDGES * 128) / 256, 256, 0, stream>>>(x2, edges, agg);
    convN_kernel<128, 256><<<NB / 64, 256, 0, stream>>>(
        x2, agg, Ws2, Wn2, b2, x3b, bidx, NB);

    // head
    hipMemsetAsync(pooled, 0, 256 * sizeof(float), stream);
    pool_kernel<<<32, 256, 0, stream>>>(x3b, pooled);
    head_kernel<<<1, 256, 0, stream>>>(pooled, bmean, Wd, bd, Wo, bo, outp);
}

// Round 4
// 559.620 us; speedup vs baseline: 1.2784x; 1.2784x over previous
//
#include <hip/hip_runtime.h>

#define N_NODES 100000
#define N_EDGES 300000
#define NB 1024

#define CAP_F1   16384      // frontier cap (expected ~7k)
#define CAP_PF   131072     // F1 pair cap (expected ~43k)
#define CAP_PB   32768      // boundary pair cap (expected ~6k)

// ---------------- workspace layout (float offsets) ----------------
#define OFF_X1      0u           // 100000*64  = 6,400,000
#define OFF_X2C     6400000u     // 16384*128  = 2,097,152
#define OFF_X3B     8497152u     // 1024*256   = 262,144
// ---- zeroed region start ----
#define OFF_AGG0    8759296u     // 100000*3   = 300,000
#define OFF_AGG1C   9059296u     // 16384*64   = 1,048,576
#define OFF_AGG2C   10107872u    // 1024*128   = 131,072
#define OFF_POOL    10238944u    // 256
#define OFF_CNT     10239200u    // 8 ints: [0]=nF1 [1]=nPairsF1 [2]=nPairsB
// ---- zeroed region end (10,239,208) ----
#define ZERO_BYTES  ((10239208u - OFF_AGG0) * 4u)
// ---- 0xFF region (slot maps = -1) ----
#define OFF_SLOTB   10239208u    // 100,000 ints
#define OFF_SLOTF1  10339208u    // 100,000 ints
#define FF_BYTES    (200000u * 4u)
#define OFF_LISTF1  10439208u    // 16,384 ints
#define OFF_PAIRSF1 10455592u    // 131,072 int2 (even float offset -> 8B aligned)
#define OFF_PAIRSB  10717736u    // 32,768 int2
#define OFF_IDXX2   10783272u    // 1024 ints
#define OFF_IDXA2   10784296u    // 1024 ints
#define OFF_BMEAN   10785320u    // 3

// boundary mean of vs -> bmean[3]
__global__ void bmean_kernel(const float* __restrict__ vs, const int* __restrict__ bidx,
                             float* __restrict__ bmean) {
    int tid = threadIdx.x;
    float s0 = 0.f, s1 = 0.f, s2 = 0.f;
    for (int i = tid; i < NB; i += 256) {
        int n = bidx[i];
        s0 += vs[n * 3 + 0];
        s1 += vs[n * 3 + 1];
        s2 += vs[n * 3 + 2];
    }
    for (int off = 32; off > 0; off >>= 1) {
        s0 += __shfl_down(s0, off);
        s1 += __shfl_down(s1, off);
        s2 += __shfl_down(s2, off);
    }
    __shared__ float red[4][3];
    int wave = tid >> 6;
    if ((tid & 63) == 0) { red[wave][0] = s0; red[wave][1] = s1; red[wave][2] = s2; }
    __syncthreads();
    if (tid == 0) {
        float t0 = 0, t1 = 0, t2 = 0;
        for (int w = 0; w < 4; w++) { t0 += red[w][0]; t1 += red[w][1]; t2 += red[w][2]; }
        bmean[0] = t0 / NB; bmean[1] = t1 / NB; bmean[2] = t2 / NB;
    }
}

__device__ __forceinline__ void claimF1(int node, int* slotF1, int* listF1, int* cnt) {
    int old = atomicCAS(&slotF1[node], -1, -2);
    if (old == -1) {
        int p = atomicAdd(&cnt[0], 1);
        if (p < CAP_F1) { listF1[p] = node; slotF1[node] = p; }
    }
}

// A: slotB map + claim boundary nodes into F1
__global__ void mark_boundary_kernel(const int* __restrict__ bidx, int* __restrict__ slotB,
                                     int* __restrict__ slotF1, int* __restrict__ listF1,
                                     int* __restrict__ cnt) {
    int i = blockIdx.x * 256 + threadIdx.x;
    if (i >= NB) return;
    int n = bidx[i];
    slotB[n] = i;           // duplicates: any winner, consistent everywhere
    claimF1(n, slotF1, listF1, cnt);
}

// B: claim neighbors of boundary into F1
__global__ void expand_frontier_kernel(const int2* __restrict__ edges,
                                       const int* __restrict__ slotB,
                                       int* __restrict__ slotF1, int* __restrict__ listF1,
                                       int* __restrict__ cnt) {
    int e = blockIdx.x * 256 + threadIdx.x;
    if (e >= N_EDGES) return;
    int2 ed = edges[e];
    if (slotB[ed.y] >= 0) claimF1(ed.x, slotF1, listF1, cnt);
    if (slotB[ed.x] >= 0) claimF1(ed.y, slotF1, listF1, cnt);
}

// C: build compacted pair lists
//  pairsF1: (src_node, dstSlotF1)  for agg1 at F1 nodes (src rows in full x1)
//  pairsB : (srcSlotF1, dstSlotB)  for agg2 at boundary nodes (src rows in compact x2c)
__global__ void build_pairs_kernel(const int2* __restrict__ edges,
                                   const int* __restrict__ slotB, const int* __restrict__ slotF1,
                                   int2* __restrict__ pairsF1, int2* __restrict__ pairsB,
                                   int* __restrict__ cnt) {
    int e = blockIdx.x * 256 + threadIdx.x;
    if (e >= N_EDGES) return;
    int2 ed = edges[e];
    int sxb = slotB[ed.x], syb = slotB[ed.y];
    int sxf = slotF1[ed.x], syf = slotF1[ed.y];
    if (syf >= 0) { int p = atomicAdd(&cnt[1], 1); if (p < CAP_PF) pairsF1[p] = make_int2(ed.x, syf); }
    if (sxf >= 0) { int p = atomicAdd(&cnt[1], 1); if (p < CAP_PF) pairsF1[p] = make_int2(ed.y, sxf); }
    if (syb >= 0) { int p = atomicAdd(&cnt[2], 1); if (p < CAP_PB) pairsB[p] = make_int2(sxf, syb); }
    if (sxb >= 0) { int p = atomicAdd(&cnt[2], 1); if (p < CAP_PB) pairsB[p] = make_int2(syf, sxb); }
}

// D: gather index arrays for conv2
__global__ void conv2_idx_kernel(const int* __restrict__ bidx, const int* __restrict__ slotB,
                                 const int* __restrict__ slotF1,
                                 int* __restrict__ idxx, int* __restrict__ idxa) {
    int i = blockIdx.x * 256 + threadIdx.x;
    if (i >= NB) return;
    int n = bidx[i];
    idxx[i] = slotF1[n];
    idxa[i] = slotB[n];
}

// full 3-channel scatter for layer 0
__global__ void scatter3_kernel(const float* __restrict__ x, const int2* __restrict__ edges,
                                float* __restrict__ agg) {
    int e = blockIdx.x * blockDim.x + threadIdx.x;
    if (e >= N_EDGES) return;
    int2 ed = edges[e];
    #pragma unroll
    for (int c = 0; c < 3; c++) {
        atomicAdd(&agg[ed.y * 3 + c], x[ed.x * 3 + c]);
        atomicAdd(&agg[ed.x * 3 + c], x[ed.y * 3 + c]);
    }
}

// conv0: 3 -> 64, relu. block = 4 nodes x 64 couts (full graph)
__global__ void conv0_kernel(const float* __restrict__ x, const float* __restrict__ agg,
                             const float* __restrict__ Ws, const float* __restrict__ Wn,
                             const float* __restrict__ b, float* __restrict__ out) {
    __shared__ float ws_l[192], wn_l[192], b_l[64];
    int tid = threadIdx.x;
    if (tid < 192) { ws_l[tid] = Ws[tid]; wn_l[tid] = Wn[tid]; }
    if (tid < 64) b_l[tid] = b[tid];
    __syncthreads();
    int n = blockIdx.x * 4 + (tid >> 6);
    int j = tid & 63;
    if (n >= N_NODES) return;
    float x0 = x[n * 3 + 0], x1v = x[n * 3 + 1], x2v = x[n * 3 + 2];
    float a0 = agg[n * 3 + 0], a1 = agg[n * 3 + 1], a2 = agg[n * 3 + 2];
    float acc = b_l[j];
    acc = fmaf(x0, ws_l[0 * 64 + j], acc);
    acc = fmaf(x1v, ws_l[1 * 64 + j], acc);
    acc = fmaf(x2v, ws_l[2 * 64 + j], acc);
    acc = fmaf(a0, wn_l[0 * 64 + j], acc);
    acc = fmaf(a1, wn_l[1 * 64 + j], acc);
    acc = fmaf(a2, wn_l[2 * 64 + j], acc);
    out[n * 64 + j] = fmaxf(acc, 0.f);
}

// grid-stride scatter over compacted pairs: agg[pair.y*C+c] += x[pair.x*C+c]
template <int LOG2C>
__global__ void scatter_pairs_kernel(const float* __restrict__ x, const int2* __restrict__ pairs,
                                     const int* __restrict__ cnt_ptr, int cap,
                                     float* __restrict__ agg) {
    const int C = 1 << LOG2C;
    int n = cnt_ptr[0];
    if (n > cap) n = cap;
    long long total = (long long)n << LOG2C;
    long long stride = (long long)gridDim.x * blockDim.x;
    for (long long wi = blockIdx.x * (long long)blockDim.x + threadIdx.x; wi < total; wi += stride) {
        int p = (int)(wi >> LOG2C);
        int c = (int)(wi & (C - 1));
        int2 pr = pairs[p];
        atomicAdd(&agg[pr.y * C + c], x[pr.x * C + c]);
    }
}

// generic conv: CIN -> COUT, relu, 64-row tile in LDS.
// x row   = idxx ? idxx[ng] : ng
// agg row = idxa ? idxa[ng] : ng
// nrows   = nrows_dev ? *nrows_dev : nrows_max
template <int CIN, int COUT>
__global__ __launch_bounds__(256) void convN_kernel(
    const float* __restrict__ x, const float* __restrict__ agg,
    const float* __restrict__ Ws, const float* __restrict__ Wn,
    const float* __restrict__ b, float* __restrict__ out,
    const int* __restrict__ idxx, const int* __restrict__ idxa,
    int nrows_max, const int* __restrict__ nrows_dev) {
    const int JT = COUT / 64;
    __shared__ float xs[64 * CIN];
    __shared__ float as[64 * CIN];
    int nrows = nrows_max;
    if (nrows_dev) { int nd = nrows_dev[0]; nrows = nd < nrows ? nd : nrows; }
    int tid = threadIdx.x;
    int gbase = blockIdx.x * 64;
    if (gbase >= nrows) return;
    for (int i = tid; i < 64 * CIN; i += 256) {
        int nl = i / CIN;
        int c = i % CIN;
        int ng = gbase + nl;
        float xv = 0.f, av = 0.f;
        if (ng < nrows) {
            int rowx = idxx ? idxx[ng] : ng;
            int rowa = idxa ? idxa[ng] : ng;
            xv = x[rowx * CIN + c];
            av = agg[rowa * CIN + c];
        }
        xs[i] = xv;
        as[i] = av;
    }
    __syncthreads();
    int j = tid & 63;
    int g = tid >> 6;
    float acc[16][JT];
    #pragma unroll
    for (int jt = 0; jt < JT; jt++) {
        float bv = b[jt * 64 + j];
        #pragma unroll
        for (int k = 0; k < 16; k++) acc[k][jt] = bv;
    }
    #pragma unroll 4
    for (int c = 0; c < CIN; c++) {
        float wsv[JT], wnv[JT];
        #pragma unroll
        for (int jt = 0; jt < JT; jt++) {
            wsv[jt] = Ws[c * COUT + jt * 64 + j];
            wnv[jt] = Wn[c * COUT + jt * 64 + j];
        }
        #pragma unroll
        for (int k = 0; k < 16; k++) {
            float xv = xs[(g * 16 + k) * CIN + c];
            float av = as[(g * 16 + k) * CIN + c];
            #pragma unroll
            for (int jt = 0; jt < JT; jt++)
                acc[k][jt] = fmaf(xv, wsv[jt], fmaf(av, wnv[jt], acc[k][jt]));
        }
    }
    #pragma unroll
    for (int k = 0; k < 16; k++) {
        int ng = gbase + g * 16 + k;
        if (ng < nrows) {
            #pragma unroll
            for (int jt = 0; jt < JT; jt++)
                out[ng * COUT + jt * 64 + j] = fmaxf(acc[k][jt], 0.f);
        }
    }
}

// pooled sum over 1024 boundary rows of x3b (compact 1024x256)
__global__ void pool_kernel(const float* __restrict__ x3b, float* __restrict__ pooled) {
    int j = threadIdx.x;
    int r0 = blockIdx.x * 32;
    float s = 0.f;
    for (int r = 0; r < 32; r++) s += x3b[(r0 + r) * 256 + j];
    atomicAdd(&pooled[j], s);
}

// head: pooled/1024 -> fc(relu) -> out(12) + bmean broadcast
__global__ void head_kernel(const float* __restrict__ pooled_sum, const float* __restrict__ bmean,
                            const float* __restrict__ Wd, const float* __restrict__ bd,
                            const float* __restrict__ Wo, const float* __restrict__ bo,
                            float* __restrict__ out) {
    __shared__ float p_l[256], h_l[256];
    int tid = threadIdx.x;
    p_l[tid] = pooled_sum[tid] * (1.0f / NB);
    __syncthreads();
    float acc = bd[tid];
    for (int c = 0; c < 256; c++) acc = fmaf(p_l[c], Wd[c * 256 + tid], acc);
    h_l[tid] = fmaxf(acc, 0.f);
    __syncthreads();
    if (tid < 12) {
        float o = bo[tid];
        for (int c = 0; c < 256; c++) o = fmaf(h_l[c], Wo[c * 12 + tid], o);
        out[tid] = o + bmean[tid % 3];
    }
}

extern "C" void kernel_launch(void* const* d_in, const int* in_sizes, int n_in,
                              void* d_out, int out_size, void* d_ws, size_t ws_size,
                              hipStream_t stream) {
    const float* vs    = (const float*)d_in[0];
    const int2*  edges = (const int2*)d_in[1];
    const int*   bidx  = (const int*)d_in[2];
    const float* Ws0 = (const float*)d_in[4];
    const float* Wn0 = (const float*)d_in[5];
    const float* b0  = (const float*)d_in[6];
    const float* Ws1 = (const float*)d_in[7];
    const float* Wn1 = (const float*)d_in[8];
    const float* b1  = (const float*)d_in[9];
    const float* Ws2 = (const float*)d_in[10];
    const float* Wn2 = (const float*)d_in[11];
    const float* b2  = (const float*)d_in[12];
    const float* Wd  = (const float*)d_in[13];
    const float* bd  = (const float*)d_in[14];
    const float* Wo  = (const float*)d_in[15];
    const float* bo  = (const float*)d_in[16];

    float* ws = (float*)d_ws;
    float* x1      = ws + OFF_X1;
    float* x2c     = ws + OFF_X2C;
    float* x3b     = ws + OFF_X3B;
    float* agg0    = ws + OFF_AGG0;
    float* agg1c   = ws + OFF_AGG1C;
    float* agg2c   = ws + OFF_AGG2C;
    float* pooled  = ws + OFF_POOL;
    int*   cnt     = (int*)(ws + OFF_CNT);
    int*   slotB   = (int*)(ws + OFF_SLOTB);
    int*   slotF1  = (int*)(ws + OFF_SLOTF1);
    int*   listF1  = (int*)(ws + OFF_LISTF1);
    int2*  pairsF1 = (int2*)(ws + OFF_PAIRSF1);
    int2*  pairsB  = (int2*)(ws + OFF_PAIRSB);
    int*   idxx2   = (int*)(ws + OFF_IDXX2);
    int*   idxa2   = (int*)(ws + OFF_IDXA2);
    float* bmean   = ws + OFF_BMEAN;
    float* outp    = (float*)d_out;

    // init: slot maps to -1, accumulators/counters to 0
    hipMemsetAsync(ws + OFF_SLOTB, 0xFF, FF_BYTES, stream);
    hipMemsetAsync(ws + OFF_AGG0, 0, ZERO_BYTES, stream);

    bmean_kernel<<<1, 256, 0, stream>>>(vs, bidx, bmean);

    // frontier construction
    mark_boundary_kernel<<<(NB + 255) / 256, 256, 0, stream>>>(bidx, slotB, slotF1, listF1, cnt);
    expand_frontier_kernel<<<(N_EDGES + 255) / 256, 256, 0, stream>>>(edges, slotB, slotF1, listF1, cnt);
    build_pairs_kernel<<<(N_EDGES + 255) / 256, 256, 0, stream>>>(edges, slotB, slotF1, pairsF1, pairsB, cnt);
    conv2_idx_kernel<<<(NB + 255) / 256, 256, 0, stream>>>(bidx, slotB, slotF1, idxx2, idxa2);

    // layer 0 (full graph, cheap)
    scatter3_kernel<<<(N_EDGES + 255) / 256, 256, 0, stream>>>(vs, edges, agg0);
    conv0_kernel<<<N_NODES / 4, 256, 0, stream>>>(vs, agg0, Ws0, Wn0, b0, x1);

    // layer 1 (agg + conv only at F1 frontier, compact)
    scatter_pairs_kernel<6><<<1024, 256, 0, stream>>>(x1, pairsF1, cnt + 1, CAP_PF, agg1c);
    convN_kernel<64, 128><<<CAP_F1 / 64, 256, 0, stream>>>(
        x1, agg1c, Ws1, Wn1, b1, x2c, listF1, nullptr, CAP_F1, cnt);

    // layer 2 (agg + conv only at boundary)
    scatter_pairs_kernel<7><<<512, 256, 0, stream>>>(x2c, pairsB, cnt + 2, CAP_PB, agg2c);
    convN_kernel<128, 256><<<NB / 64, 256, 0, stream>>>(
        x2c, agg2c, Ws2, Wn2, b2, x3b, idxx2, idxa2, NB, nullptr);

    // head
    pool_kernel<<<32, 256, 0, stream>>>(x3b, pooled);
    head_kernel<<<1, 256, 0, stream>>>(pooled, bmean, Wd, bd, Wo, bo, outp);
}

// Round 6
// 396.856 us; speedup vs baseline: 1.8027x; 1.4101x over previous
//
#include <hip/hip_runtime.h>

#define N_NODES 100000
#define N_EDGES 300000
#define NB 1024

#define CAP_F1   16384      // frontier cap (expected ~7k)
#define CAP_PF   131072     // F1 pair cap (expected ~43k)
#define CAP_PB   32768      // boundary pair cap (expected ~6k)

// padded counter indices (separate cachelines to avoid atomic false sharing)
#define CNT_F1   0
#define CNT_PF   16
#define CNT_PB   32

// ---------------- workspace layout (float offsets) ----------------
#define OFF_X1      0u           // 100000*64  = 6,400,000
#define OFF_X2C     6400000u     // 16384*128  = 2,097,152
#define OFF_X3B     8497152u     // 1024*256   = 262,144
// ---- zeroed region start ----
#define OFF_AGG0    8759296u     // 100000*3   = 300,000
#define OFF_AGG1C   9059296u     // 16384*64   = 1,048,576
#define OFF_AGG2C   10107872u    // 1024*128   = 131,072
#define OFF_POOL    10238944u    // 256
#define OFF_CNT     10239200u    // 64 ints (padded counters)
// ---- zeroed region end (10,239,264) ----
#define ZERO_BYTES  ((10239264u - OFF_AGG0) * 4u)
// ---- 0xFF region (slot maps = -1) ----
#define OFF_SLOTB   10239264u    // 100,000 ints
#define OFF_SLOTF1  10339264u    // 100,000 ints
#define FF_BYTES    (200000u * 4u)
#define OFF_LISTF1  10439264u    // 16,384 ints
#define OFF_PAIRSF1 10455648u    // 131,072 int2 (even float offset -> 8B aligned)
#define OFF_PAIRSB  10717792u    // 32,768 int2
#define OFF_IDXX2   10783328u    // 1024 ints
#define OFF_IDXA2   10784352u    // 1024 ints
#define OFF_BMEAN   10785376u    // 3

// boundary mean of vs -> bmean[3]
__global__ void bmean_kernel(const float* __restrict__ vs, const int* __restrict__ bidx,
                             float* __restrict__ bmean) {
    int tid = threadIdx.x;
    float s0 = 0.f, s1 = 0.f, s2 = 0.f;
    for (int i = tid; i < NB; i += 256) {
        int n = bidx[i];
        s0 += vs[n * 3 + 0];
        s1 += vs[n * 3 + 1];
        s2 += vs[n * 3 + 2];
    }
    for (int off = 32; off > 0; off >>= 1) {
        s0 += __shfl_down(s0, off);
        s1 += __shfl_down(s1, off);
        s2 += __shfl_down(s2, off);
    }
    __shared__ float red[4][3];
    int wave = tid >> 6;
    if ((tid & 63) == 0) { red[wave][0] = s0; red[wave][1] = s1; red[wave][2] = s2; }
    __syncthreads();
    if (tid == 0) {
        float t0 = 0, t1 = 0, t2 = 0;
        for (int w = 0; w < 4; w++) { t0 += red[w][0]; t1 += red[w][1]; t2 += red[w][2]; }
        bmean[0] = t0 / NB; bmean[1] = t1 / NB; bmean[2] = t2 / NB;
    }
}

// wave-aggregated F1 claim: CAS per node (uncontended), ONE cnt atomic per wave.
// All 64 lanes of the wave must reach this call (no early return at call sites).
__device__ __forceinline__ void claimF1(bool want, int node, int* slotF1, int* listF1, int* cnt) {
    bool won = false;
    if (want) won = (atomicCAS(&slotF1[node], -1, -2) == -1);
    unsigned long long m = __ballot(won);
    if (m == 0ull) return;
    int lane = threadIdx.x & 63;
    int leader = __ffsll((unsigned long long)m) - 1;
    int base = 0;
    if (lane == leader) base = atomicAdd(&cnt[CNT_F1], __popcll(m));
    base = __shfl(base, leader);
    if (won) {
        int p = base + __popcll(m & ((1ull << lane) - 1));
        if (p < CAP_F1) { listF1[p] = node; slotF1[node] = p; }
        // p >= cap: slot stays -2 (excluded), same semantics as before
    }
}

// A: slotB map + claim boundary nodes into F1
__global__ void mark_boundary_kernel(const int* __restrict__ bidx, int* __restrict__ slotB,
                                     int* __restrict__ slotF1, int* __restrict__ listF1,
                                     int* __restrict__ cnt) {
    int i = blockIdx.x * 256 + threadIdx.x;
    bool valid = i < NB;
    int n = valid ? bidx[i] : 0;
    if (valid) slotB[n] = i;           // duplicates: any winner, consistent everywhere
    claimF1(valid, n, slotF1, listF1, cnt);
}

// B: claim neighbors of boundary into F1
__global__ void expand_frontier_kernel(const int2* __restrict__ edges,
                                       const int* __restrict__ slotB,
                                       int* __restrict__ slotF1, int* __restrict__ listF1,
                                       int* __restrict__ cnt) {
    int e = blockIdx.x * 256 + threadIdx.x;
    bool valid = e < N_EDGES;
    int2 ed = valid ? edges[e] : make_int2(0, 0);
    bool wy = valid && (slotB[ed.y] >= 0);
    bool wx = valid && (slotB[ed.x] >= 0);
    claimF1(wy, ed.x, slotF1, listF1, cnt);
    claimF1(wx, ed.y, slotF1, listF1, cnt);
}

// C: build compacted pair lists, block-aggregated slot allocation.
//  pairsF1: (src_node, dstSlotF1)  for agg1 at F1 nodes (src rows in full x1)
//  pairsB : (srcSlotF1, dstSlotB)  for agg2 at boundary nodes (src rows in compact x2c)
__global__ __launch_bounds__(256) void build_pairs_kernel(
        const int2* __restrict__ edges,
        const int* __restrict__ slotB, const int* __restrict__ slotF1,
        int2* __restrict__ pairsF1, int2* __restrict__ pairsB,
        int* __restrict__ cnt) {
    int e = blockIdx.x * 256 + threadIdx.x;
    bool p0 = false, p1 = false, p2 = false, p3 = false;
    int2 pr0 = make_int2(0, 0), pr1 = pr0, pr2 = pr0, pr3 = pr0;
    if (e < N_EDGES) {
        int2 ed = edges[e];
        int sxb = slotB[ed.x], syb = slotB[ed.y];
        int sxf = slotF1[ed.x], syf = slotF1[ed.y];
        p0 = syf >= 0; pr0 = make_int2(ed.x, syf);
        p1 = sxf >= 0; pr1 = make_int2(ed.y, sxf);
        p2 = syb >= 0; pr2 = make_int2(sxf, syb);
        p3 = sxb >= 0; pr3 = make_int2(syf, sxb);
    }
    int wave = threadIdx.x >> 6;
    int lane = threadIdx.x & 63;
    unsigned long long below = (1ull << lane) - 1;
    __shared__ int s_w[4][4];    // [cond][wave]: counts, then exclusive offsets
    __shared__ int s_base[4];
    unsigned long long m0 = __ballot(p0), m1 = __ballot(p1);
    unsigned long long m2 = __ballot(p2), m3 = __ballot(p3);
    int r0 = __popcll(m0 & below), r1 = __popcll(m1 & below);
    int r2 = __popcll(m2 & below), r3 = __popcll(m3 & below);
    if (lane == 0) {
        s_w[0][wave] = __popcll(m0);
        s_w[1][wave] = __popcll(m1);
        s_w[2][wave] = __popcll(m2);
        s_w[3][wave] = __popcll(m3);
    }
    __syncthreads();
    if (threadIdx.x == 0) {
        int tot[4];
        #pragma unroll
        for (int c = 0; c < 4; c++) {
            int s = 0;
            #pragma unroll
            for (int w = 0; w < 4; w++) { int v = s_w[c][w]; s_w[c][w] = s; s += v; }
            tot[c] = s;
        }
        int baseF = (tot[0] + tot[1]) ? atomicAdd(&cnt[CNT_PF], tot[0] + tot[1]) : 0;
        int baseB = (tot[2] + tot[3]) ? atomicAdd(&cnt[CNT_PB], tot[2] + tot[3]) : 0;
        s_base[0] = baseF; s_base[1] = baseF + tot[0];
        s_base[2] = baseB; s_base[3] = baseB + tot[2];
    }
    __syncthreads();
    if (p0) { int p = s_base[0] + s_w[0][wave] + r0; if (p < CAP_PF) pairsF1[p] = pr0; }
    if (p1) { int p = s_base[1] + s_w[1][wave] + r1; if (p < CAP_PF) pairsF1[p] = pr1; }
    if (p2) { int p = s_base[2] + s_w[2][wave] + r2; if (p < CAP_PB) pairsB[p] = pr2; }
    if (p3) { int p = s_base[3] + s_w[3][wave] + r3; if (p < CAP_PB) pairsB[p] = pr3; }
}

// D: gather index arrays for conv2
__global__ void conv2_idx_kernel(const int* __restrict__ bidx, const int* __restrict__ slotB,
                                 const int* __restrict__ slotF1,
                                 int* __restrict__ idxx, int* __restrict__ idxa) {
    int i = blockIdx.x * 256 + threadIdx.x;
    if (i >= NB) return;
    int n = bidx[i];
    idxx[i] = slotF1[n];
    idxa[i] = slotB[n];
}

// full 3-channel scatter for layer 0
__global__ void scatter3_kernel(const float* __restrict__ x, const int2* __restrict__ edges,
                                float* __restrict__ agg) {
    int e = blockIdx.x * blockDim.x + threadIdx.x;
    if (e >= N_EDGES) return;
    int2 ed = edges[e];
    #pragma unroll
    for (int c = 0; c < 3; c++) {
        atomicAdd(&agg[ed.y * 3 + c], x[ed.x * 3 + c]);
        atomicAdd(&agg[ed.x * 3 + c], x[ed.y * 3 + c]);
    }
}

// conv0: 3 -> 64, relu. block = 4 nodes x 64 couts (full graph)
__global__ void conv0_kernel(const float* __restrict__ x, const float* __restrict__ agg,
                             const float* __restrict__ Ws, const float* __restrict__ Wn,
                             const float* __restrict__ b, float* __restrict__ out) {
    __shared__ float ws_l[192], wn_l[192], b_l[64];
    int tid = threadIdx.x;
    if (tid < 192) { ws_l[tid] = Ws[tid]; wn_l[tid] = Wn[tid]; }
    if (tid < 64) b_l[tid] = b[tid];
    __syncthreads();
    int n = blockIdx.x * 4 + (tid >> 6);
    int j = tid & 63;
    if (n >= N_NODES) return;
    float x0 = x[n * 3 + 0], x1v = x[n * 3 + 1], x2v = x[n * 3 + 2];
    float a0 = agg[n * 3 + 0], a1 = agg[n * 3 + 1], a2 = agg[n * 3 + 2];
    float acc = b_l[j];
    acc = fmaf(x0, ws_l[0 * 64 + j], acc);
    acc = fmaf(x1v, ws_l[1 * 64 + j], acc);
    acc = fmaf(x2v, ws_l[2 * 64 + j], acc);
    acc = fmaf(a0, wn_l[0 * 64 + j], acc);
    acc = fmaf(a1, wn_l[1 * 64 + j], acc);
    acc = fmaf(a2, wn_l[2 * 64 + j], acc);
    out[n * 64 + j] = fmaxf(acc, 0.f);
}

// grid-stride scatter over compacted pairs: agg[pair.y*C+c] += x[pair.x*C+c]
template <int LOG2C>
__global__ void scatter_pairs_kernel(const float* __restrict__ x, const int2* __restrict__ pairs,
                                     const int* __restrict__ cnt_ptr, int cap,
                                     float* __restrict__ agg) {
    const int C = 1 << LOG2C;
    int n = cnt_ptr[0];
    if (n > cap) n = cap;
    long long total = (long long)n << LOG2C;
    long long stride = (long long)gridDim.x * blockDim.x;
    for (long long wi = blockIdx.x * (long long)blockDim.x + threadIdx.x; wi < total; wi += stride) {
        int p = (int)(wi >> LOG2C);
        int c = (int)(wi & (C - 1));
        int2 pr = pairs[p];
        atomicAdd(&agg[pr.y * C + c], x[pr.x * C + c]);
    }
}

// generic conv: CIN -> COUT, relu, 64-row tile in LDS.
// x row   = idxx ? idxx[ng] : ng
// agg row = idxa ? idxa[ng] : ng
// nrows   = nrows_dev ? *nrows_dev : nrows_max
template <int CIN, int COUT>
__global__ __launch_bounds__(256) void convN_kernel(
    const float* __restrict__ x, const float* __restrict__ agg,
    const float* __restrict__ Ws, const float* __restrict__ Wn,
    const float* __restrict__ b, float* __restrict__ out,
    const int* __restrict__ idxx, const int* __restrict__ idxa,
    int nrows_max, const int* __restrict__ nrows_dev) {
    const int JT = COUT / 64;
    __shared__ float xs[64 * CIN];
    __shared__ float as[64 * CIN];
    int nrows = nrows_max;
    if (nrows_dev) { int nd = nrows_dev[0]; nrows = nd < nrows ? nd : nrows; }
    int tid = threadIdx.x;
    int gbase = blockIdx.x * 64;
    if (gbase >= nrows) return;
    for (int i = tid; i < 64 * CIN; i += 256) {
        int nl = i / CIN;
        int c = i % CIN;
        int ng = gbase + nl;
        float xv = 0.f, av = 0.f;
        if (ng < nrows) {
            int rowx = idxx ? idxx[ng] : ng;
            int rowa = idxa ? idxa[ng] : ng;
            xv = x[rowx * CIN + c];
            av = agg[rowa * CIN + c];
        }
        xs[i] = xv;
        as[i] = av;
    }
    __syncthreads();
    int j = tid & 63;
    int g = tid >> 6;
    float acc[16][JT];
    #pragma unroll
    for (int jt = 0; jt < JT; jt++) {
        float bv = b[jt * 64 + j];
        #pragma unroll
        for (int k = 0; k < 16; k++) acc[k][jt] = bv;
    }
    #pragma unroll 4
    for (int c = 0; c < CIN; c++) {
        float wsv[JT], wnv[JT];
        #pragma unroll
        for (int jt = 0; jt < JT; jt++) {
            wsv[jt] = Ws[c * COUT + jt * 64 + j];
            wnv[jt] = Wn[c * COUT + jt * 64 + j];
        }
        #pragma unroll
        for (int k = 0; k < 16; k++) {
            float xv = xs[(g * 16 + k) * CIN + c];
            float av = as[(g * 16 + k) * CIN + c];
            #pragma unroll
            for (int jt = 0; jt < JT; jt++)
                acc[k][jt] = fmaf(xv, wsv[jt], fmaf(av, wnv[jt], acc[k][jt]));
        }
    }
    #pragma unroll
    for (int k = 0; k < 16; k++) {
        int ng = gbase + g * 16 + k;
        if (ng < nrows) {
            #pragma unroll
            for (int jt = 0; jt < JT; jt++)
                out[ng * COUT + jt * 64 + j] = fmaxf(acc[k][jt], 0.f);
        }
    }
}

// pooled sum over 1024 boundary rows of x3b (compact 1024x256)
__global__ void pool_kernel(const float* __restrict__ x3b, float* __restrict__ pooled) {
    int j = threadIdx.x;
    int r0 = blockIdx.x * 32;
    float s = 0.f;
    for (int r = 0; r < 32; r++) s += x3b[(r0 + r) * 256 + j];
    atomicAdd(&pooled[j], s);
}

// head: pooled/1024 -> fc(relu) -> out(12) + bmean broadcast
__global__ void head_kernel(const float* __restrict__ pooled_sum, const float* __restrict__ bmean,
                            const float* __restrict__ Wd, const float* __restrict__ bd,
                            const float* __restrict__ Wo, const float* __restrict__ bo,
                            float* __restrict__ out) {
    __shared__ float p_l[256], h_l[256];
    int tid = threadIdx.x;
    p_l[tid] = pooled_sum[tid] * (1.0f / NB);
    __syncthreads();
    float acc = bd[tid];
    for (int c = 0; c < 256; c++) acc = fmaf(p_l[c], Wd[c * 256 + tid], acc);
    h_l[tid] = fmaxf(acc, 0.f);
    __syncthreads();
    if (tid < 12) {
        float o = bo[tid];
        for (int c = 0; c < 256; c++) o = fmaf(h_l[c], Wo[c * 12 + tid], o);
        out[tid] = o + bmean[tid % 3];
    }
}

extern "C" void kernel_launch(void* const* d_in, const int* in_sizes, int n_in,
                              void* d_out, int out_size, void* d_ws, size_t ws_size,
                              hipStream_t stream) {
    const float* vs    = (const float*)d_in[0];
    const int2*  edges = (const int2*)d_in[1];
    const int*   bidx  = (const int*)d_in[2];
    const float* Ws0 = (const float*)d_in[4];
    const float* Wn0 = (const float*)d_in[5];
    const float* b0  = (const float*)d_in[6];
    const float* Ws1 = (const float*)d_in[7];
    const float* Wn1 = (const float*)d_in[8];
    const float* b1  = (const float*)d_in[9];
    const float* Ws2 = (const float*)d_in[10];
    const float* Wn2 = (const float*)d_in[11];
    const float* b2  = (const float*)d_in[12];
    const float* Wd  = (const float*)d_in[13];
    const float* bd  = (const float*)d_in[14];
    const float* Wo  = (const float*)d_in[15];
    const float* bo  = (const float*)d_in[16];

    float* ws = (float*)d_ws;
    float* x1      = ws + OFF_X1;
    float* x2c     = ws + OFF_X2C;
    float* x3b     = ws + OFF_X3B;
    float* agg0    = ws + OFF_AGG0;
    float* agg1c   = ws + OFF_AGG1C;
    float* agg2c   = ws + OFF_AGG2C;
    float* pooled  = ws + OFF_POOL;
    int*   cnt     = (int*)(ws + OFF_CNT);
    int*   slotB   = (int*)(ws + OFF_SLOTB);
    int*   slotF1  = (int*)(ws + OFF_SLOTF1);
    int*   listF1  = (int*)(ws + OFF_LISTF1);
    int2*  pairsF1 = (int2*)(ws + OFF_PAIRSF1);
    int2*  pairsB  = (int2*)(ws + OFF_PAIRSB);
    int*   idxx2   = (int*)(ws + OFF_IDXX2);
    int*   idxa2   = (int*)(ws + OFF_IDXA2);
    float* bmean   = ws + OFF_BMEAN;
    float* outp    = (float*)d_out;

    // init: slot maps to -1, accumulators/counters to 0
    hipMemsetAsync(ws + OFF_SLOTB, 0xFF, FF_BYTES, stream);
    hipMemsetAsync(ws + OFF_AGG0, 0, ZERO_BYTES, stream);

    bmean_kernel<<<1, 256, 0, stream>>>(vs, bidx, bmean);

    // frontier construction
    mark_boundary_kernel<<<(NB + 255) / 256, 256, 0, stream>>>(bidx, slotB, slotF1, listF1, cnt);
    expand_frontier_kernel<<<(N_EDGES + 255) / 256, 256, 0, stream>>>(edges, slotB, slotF1, listF1, cnt);
    build_pairs_kernel<<<(N_EDGES + 255) / 256, 256, 0, stream>>>(edges, slotB, slotF1, pairsF1, pairsB, cnt);
    conv2_idx_kernel<<<(NB + 255) / 256, 256, 0, stream>>>(bidx, slotB, slotF1, idxx2, idxa2);

    // layer 0 (full graph, cheap)
    scatter3_kernel<<<(N_EDGES + 255) / 256, 256, 0, stream>>>(vs, edges, agg0);
    conv0_kernel<<<N_NODES / 4, 256, 0, stream>>>(vs, agg0, Ws0, Wn0, b0, x1);

    // layer 1 (agg + conv only at F1 frontier, compact)
    scatter_pairs_kernel<6><<<1024, 256, 0, stream>>>(x1, pairsF1, cnt + CNT_PF, CAP_PF, agg1c);
    convN_kernel<64, 128><<<CAP_F1 / 64, 256, 0, stream>>>(
        x1, agg1c, Ws1, Wn1, b1, x2c, listF1, nullptr, CAP_F1, cnt + CNT_F1);

    // layer 2 (agg + conv only at boundary)
    scatter_pairs_kernel<7><<<512, 256, 0, stream>>>(x2c, pairsB, cnt + CNT_PB, CAP_PB, agg2c);
    convN_kernel<128, 256><<<NB / 64, 256, 0, stream>>>(
        x2c, agg2c, Ws2, Wn2, b2, x3b, idxx2, idxa2, NB, nullptr);

    // head
    pool_kernel<<<32, 256, 0, stream>>>(x3b, pooled);
    head_kernel<<<1, 256, 0, stream>>>(pooled, bmean, Wd, bd, Wo, bo, outp);
}